// Round 2
// baseline (866.652 us; speedup 1.0000x reference)
//
#include <hip/hip_runtime.h>
#include <stdint.h>

// Problem constants (from reference setup_inputs)
#define M_TOK 8192
#define N_OUT 4096
#define K_IN  4096

// GEMM tiling
#define BM 128
#define BN 128
#define BK 64   // 32 KiB LDS total (16K A + 16K B bf16), single-buffered

typedef float floatx4 __attribute__((ext_vector_type(4)));
typedef __bf16 bf16x8 __attribute__((ext_vector_type(8)));
typedef unsigned short ushort8_t __attribute__((ext_vector_type(8)));

// ---------- helpers ----------

__device__ __forceinline__ unsigned short f32_to_bf16_rne(float f) {
    union { float f; unsigned int u; } v; v.f = f;
    unsigned int u = v.u;
    u += 0x7FFFu + ((u >> 16) & 1u);   // round-to-nearest-even; inputs have no NaN
    return (unsigned short)(u >> 16);
}

// two fp32 -> packed bf16x2 (low ushort = x), RNE, via v_perm_b32
__device__ __forceinline__ unsigned int pack_bf16x2(float x, float y) {
    union { float f; unsigned int u; } a, b; a.f = x; b.f = y;
    unsigned int ra = a.u + (0x7FFFu + ((a.u >> 16) & 1u));
    unsigned int rb = b.u + (0x7FFFu + ((b.u >> 16) & 1u));
    // D.b[0..3] = ra.b2, ra.b3, rb.b2, rb.b3  (sel 0-3 -> S1=ra, 4-7 -> S0=rb)
    return __builtin_amdgcn_perm(rb, ra, 0x07060302);
}

// async global->LDS, 16 bytes per lane. LDS side is wave-uniform base + lane*16.
__device__ __forceinline__ void async_copy16(const void* g, void* l) {
    __builtin_amdgcn_global_load_lds(
        (__attribute__((address_space(1))) void*)(g),
        (__attribute__((address_space(3))) void*)(l),
        16, 0, 0);
}

// ---------- pre-pass: int32 (int8-valued) -> bf16 (exact) ----------

__global__ void cvt_i32_bf16_kernel(const int* __restrict__ in,
                                    unsigned short* __restrict__ out, int n8) {
    int i = blockIdx.x * 256 + threadIdx.x;
    if (i >= n8) return;
    const int4* p = (const int4*)in + (size_t)i * 2;
    int4 a = p[0];
    int4 b = p[1];
    ushort8_t o;
    o[0] = f32_to_bf16_rne((float)a.x); o[1] = f32_to_bf16_rne((float)a.y);
    o[2] = f32_to_bf16_rne((float)a.z); o[3] = f32_to_bf16_rne((float)a.w);
    o[4] = f32_to_bf16_rne((float)b.x); o[5] = f32_to_bf16_rne((float)b.y);
    o[6] = f32_to_bf16_rne((float)b.z); o[7] = f32_to_bf16_rne((float)b.w);
    *((ushort8_t*)out + i) = o;
}

// ---------- GEMM: C[m][n] = sum_k x[m][k]*W[n][k]; C = acc*scale[n]+bias[n] ----------
// x: [M][K] fp32 row-major (converted to bf16 in-register during A staging).
// W: [N][K] bf16 row-major (pre-converted), staged via global_load_lds.
// Block: 256 threads = 4 waves in 2x2; each wave does 64x64 via 4x4 MFMA 16x16x32.
// LDS col-block XOR swizzle (both tiles): LDS slot (row, cb) holds global
// (row, cb ^ (row&7)), cb = 8-bf16 (16 B) column block in [0,8).
//   - B gather side: free (we pick the global chunk per lane).
//   - A scatter side: regular ds_write_b128 per lane, swizzled address.
//   - Fragment reads XOR the same term back (loop-invariant).

__global__ __launch_bounds__(256)
void gemm_bf16_kernel(const float* __restrict__ X,
                      const unsigned short* __restrict__ B,
                      const float* __restrict__ scales,
                      const float* __restrict__ bias,
                      float* __restrict__ C) {
    __shared__ __align__(16) unsigned short As[BM * BK];
    __shared__ __align__(16) unsigned short Bs[BN * BK];

    const int tid  = threadIdx.x;
    const int bn   = blockIdx.x & 31;          // N_OUT/BN = 32
    const int bm   = blockIdx.x >> 5;
    const int lane = tid & 63;
    const int wave = tid >> 6;
    const int wm   = (wave >> 1) * 64;
    const int wn   = (wave & 1) * 64;

    // ---- B staging addressing (global_load_lds, loop-invariant) ----
    // chunk id c = issue*256 + tid; LDS row = c>>3 (issue advances row by 32,
    // preserving row&7), LDS col-block = c&7. Global col-block = (c&7)^(row&7).
    const int srow  = tid >> 3;                       // 0..31
    const int gcb   = (tid & 7) ^ (srow & 7);         // swizzled global col block
    const unsigned short* bptr =
        B + (size_t)(bn * BN + srow) * K_IN + gcb * 8;
    unsigned short* bs_st = Bs + tid * 8;             // advances 256*8 per issue

    // ---- A staging addressing (fp32 -> bf16 through VGPRs) ----
    // thread t: row = t>>1 (0..127), half = t&1 covers 32 fp32 cols (128 B).
    const int arow  = tid >> 1;
    const int ahalf = tid & 1;
    const float* a_g = X + (size_t)(bm * BM + arow) * K_IN + ahalf * 32;
    unsigned short* a_l = As + arow * BK;
    const int r7 = arow & 7;

    // ---- fragment read addressing (loop-invariant) ----
    // A frag (16x16x32): row = lane&15, k = (lane>>4)*8 + j.  Same for B.
    // element col = s*32 + (lane>>4)*8 -> cb = s*4 + (lane>>4); row&7 = lane&7.
    const int frag_r = lane & 15;
    const int q      = lane >> 4;                     // 0..3
    const int koff0  = ((q    ) ^ (lane & 7)) * 8;    // s = 0
    const int koff1  = ((q + 4) ^ (lane & 7)) * 8;    // s = 1
    const unsigned short* a_rd = As + (wm + frag_r) * BK;
    const unsigned short* b_rd = Bs + (wn + frag_r) * BK;

    floatx4 acc[4][4] = {};

    for (int k0 = 0; k0 < K_IN; k0 += BK) {
        // B: fire-and-forget DMA to LDS
#pragma unroll
        for (int i = 0; i < 4; ++i)
            async_copy16(bptr + (size_t)i * 32 * K_IN + k0, bs_st + i * 2048);

        // A: fp32 global -> VGPR -> bf16 -> swizzled LDS (two rounds bound
        // the live range to 4 dwordx4 + 2 packed uint4 at a time)
#pragma unroll
        for (int r = 0; r < 2; ++r) {
            const float4* p = (const float4*)(a_g + k0 + r * 16);
            float4 f0 = p[0], f1 = p[1], f2 = p[2], f3 = p[3];
            uint4 w0, w1;
            w0.x = pack_bf16x2(f0.x, f0.y); w0.y = pack_bf16x2(f0.z, f0.w);
            w0.z = pack_bf16x2(f1.x, f1.y); w0.w = pack_bf16x2(f1.z, f1.w);
            w1.x = pack_bf16x2(f2.x, f2.y); w1.y = pack_bf16x2(f2.z, f2.w);
            w1.z = pack_bf16x2(f3.x, f3.y); w1.w = pack_bf16x2(f3.z, f3.w);
            const int cb0 = (ahalf * 4 + r * 2)     ^ r7;
            const int cb1 = (ahalf * 4 + r * 2 + 1) ^ r7;
            *(uint4*)(a_l + cb0 * 8) = w0;
            *(uint4*)(a_l + cb1 * 8) = w1;
        }
        __syncthreads();   // drains vmcnt (B DMA) + lgkmcnt (A ds_writes)

#pragma unroll
        for (int s = 0; s < 2; ++s) {
            const int ko = s ? koff1 : koff0;
            bf16x8 af[4], bfr[4];
#pragma unroll
            for (int i = 0; i < 4; ++i)
                af[i] = *(const bf16x8*)(a_rd + i * 16 * BK + ko);
#pragma unroll
            for (int j = 0; j < 4; ++j)
                bfr[j] = *(const bf16x8*)(b_rd + j * 16 * BK + ko);
#pragma unroll
            for (int i = 0; i < 4; ++i)
#pragma unroll
                for (int j = 0; j < 4; ++j)
                    acc[i][j] = __builtin_amdgcn_mfma_f32_16x16x32_bf16(
                        af[i], bfr[j], acc[i][j], 0, 0, 0);
        }
        __syncthreads();   // protect LDS before next stage overwrites
    }

    // ---- epilogue: C/D layout col = lane&15, row = (lane>>4)*4 + reg ----
    const int row_base = bm * BM + wm + q * 4;
    const int col_base = bn * BN + wn + (lane & 15);
#pragma unroll
    for (int j = 0; j < 4; ++j) {
        const int n  = col_base + j * 16;
        const float sc = scales[n];
        const float bi = bias[n];
#pragma unroll
        for (int i = 0; i < 4; ++i) {
            const int m = row_base + i * 16;
#pragma unroll
            for (int r = 0; r < 4; ++r)
                C[(size_t)(m + r) * N_OUT + n] = acc[i][j][r] * sc + bi;
        }
    }
}

// ---------- launch ----------

extern "C" void kernel_launch(void* const* d_in, const int* in_sizes, int n_in,
                              void* d_out, int out_size, void* d_ws, size_t ws_size,
                              hipStream_t stream) {
    const float* x      = (const float*)d_in[0];
    const int*   wq     = (const int*)d_in[1];
    const float* scales = (const float*)d_in[2];
    const float* bias   = (const float*)d_in[3];
    float*       out    = (float*)d_out;

    unsigned short* wb = (unsigned short*)d_ws;   // 32 MiB bf16 weights

    const int nw8 = (N_OUT * K_IN) / 8;   // 2097152
    cvt_i32_bf16_kernel<<<nw8 / 256, 256, 0, stream>>>(wq, wb, nw8);

    const int grid = (M_TOK / BM) * (N_OUT / BN);   // 64 * 32 = 2048
    gemm_bf16_kernel<<<grid, 256, 0, stream>>>(x, wb, scales, bias, out);
}